// Round 2
// baseline (1003.213 us; speedup 1.0000x reference)
//
#include <hip/hip_runtime.h>

// Problem constants (reference: E,D,H,N = 16,1024,4096,16384; uniform counts)
#define E_  16
#define D_  1024
#define H_  4096
#define NPE 1024  // tokens per expert = N/E

typedef __bf16 bf16x8 __attribute__((ext_vector_type(8)));
typedef float f32x4 __attribute__((ext_vector_type(4)));

__device__ __forceinline__ unsigned short f2bf(float f) {
  unsigned int u = __float_as_uint(f);
  u += 0x7fffu + ((u >> 16) & 1u);  // RNE
  return (unsigned short)(u >> 16);
}

// fp32 -> bf16 convert. R2: grid-stride (2048 blocks) instead of one-shot
// 65536-block launch. R1 showed ~170us/dispatch vs 64us BW roofline: one
// float4 per thread = latency-bound block turnover. Grid-stride + unroll
// gives each thread 8-32 independent 16B loads -> BW-bound.
__global__ __launch_bounds__(256) void cvt_f32_to_bf16(
    const float* __restrict__ in, unsigned short* __restrict__ out, int nvec) {
  const int stride = gridDim.x * 256;
#pragma unroll 4
  for (int i = blockIdx.x * 256 + threadIdx.x; i < nvec; i += stride) {
    float4 v = ((const float4*)in)[i];
    ushort4 o;
    o.x = f2bf(v.x);
    o.y = f2bf(v.y);
    o.z = f2bf(v.z);
    o.w = f2bf(v.w);
    ((ushort4*)out)[i] = o;
  }
}

// Raw workgroup barrier (no vmcnt/lgkmcnt drain) with compiler memory fences
// on both sides so LDS/global ops can't be moved across it at IR level.
__device__ __forceinline__ void wg_barrier() {
  asm volatile("" ::: "memory");
  __builtin_amdgcn_s_barrier();
  asm volatile("" ::: "memory");
}

// Batched NT GEMM: C[e] = A[e] (MxK row-major) * B[e]^T (B NxK row-major)
//                  + bias[e], optional ReLU + bf16 output.
//
// R2 structure: 256x256 tile, BK=32, 512 threads = 8 waves (2M x 4N), each
// wave owns 128x64 (acc[8][4] of 16x16x32 MFMA). 4 LDS K-tile buffers
// (128KB), prefetch depth 3 via global_load_lds width=16, counted
// s_waitcnt vmcnt(12) once per K-tile (never 0 in the loop).
//
// R2 change vs R1 (which measured 602 TF, MfmaUtil 24.5%): R1 had 4
// barriers/K-tile and issued phase-B ds_reads only after the post-MFMA-A
// barrier -> LDS unit idle during MFMA, matrix pipe idle during reads
// (pipes alternated; 4274 cyc/K-tile vs ~1300 overlapped). Now: only the
// two CORRECTNESS barriers remain (post-vmcnt: all waves' staging of tile
// kt visible; end-of-tile: all waves done reading before buf recycle).
// All 12 ds_read_b128 are issued up front; the compiler's fine-grained
// lgkmcnt (m97-verified behavior) leaves the a1[] reads outstanding while
// the first 16 MFMA run, overlapping LDS drain with the matrix pipe.
// setprio(1) spans the MFMA region (T5).
//
// vmcnt(12) correctness: 4 loads/thread/tile, in-order retirement; after
// STAGE(kt+3), <=12 outstanding implies tile kt fully landed. Holds in the
// tail (fewer, newer loads). Requires nK>=3 (K=1024/4096 ok) and no
// scratch spills (VGPR ~200 < 256 at 2 waves/SIMD bound).
//
// Buffer recycle: STAGE(kt+3) writes buf[(kt-1)&3]; every wave's reads of
// that buffer completed before it passed the END barrier of iter kt-1
// (reads are consumed by MFMAs that precede the barrier in program order).
template <bool RELU_BF16_OUT>
__global__ __launch_bounds__(512, 2) void gemm_bt(
    const unsigned short* __restrict__ A,   // [E][M][K] bf16
    const unsigned short* __restrict__ B,   // [E][N][K] bf16
    const float* __restrict__ bias,         // [E][N]
    void* __restrict__ Cout,                // [E][M][N] bf16 or f32
    int M, int N, int K) {
  __shared__ __attribute__((aligned(16))) unsigned short ldsA[4 * 256 * 32];
  __shared__ __attribute__((aligned(16))) unsigned short ldsB[4 * 256 * 32];

  const int tid  = threadIdx.x;
  const int lane = tid & 63;
  const int wave = tid >> 6;   // 0..7
  const int wm   = wave >> 2;  // 0..1
  const int wn   = wave & 3;   // 0..3
  const int fr   = lane & 15;  // fragment row/col within 16
  const int fq   = lane >> 4;  // quad 0..3

  // ---- XCD-aware tile decode (1D grid: E * Mt * Nt blocks, 256^2 tiles) ----
  const int Mt = M >> 8;
  const int Nt = N >> 8;
  const int id     = blockIdx.x;
  const int region = id & 7;       // dispatch round-robins XCDs (R1-measured)
  const int slot   = id >> 3;
  const int bpe    = Mt * Nt;
  const int eloc   = slot / bpe;
  const int rem    = slot - eloc * bpe;
  const int e      = region * (E_ / 8) + eloc;
  const int SN     = Nt < 2 ? Nt : 2;
  const int csz    = Mt * SN;
  const int chunk  = rem / csz;
  const int inner  = rem - chunk * csz;
  const int mt     = inner % Mt;   // mt fastest within supertile
  const int nt     = chunk * SN + inner / Mt;

  const int bm = mt << 8;
  const int bn = nt << 8;

  const unsigned short* Ae = A + (size_t)e * M * K;
  const unsigned short* Be = B + (size_t)e * N * K;

  // ---- staging: 4 x global_load_lds width-16 per thread per K-tile.
  // Linear LDS dest (HW adds lane*16B); source chunk pre-swizzled so that
  // physical chunk p at row r holds logical chunk p^((r>>1)&3) (T2, R1:
  // SQ_LDS_BANK_CONFLICT == 0).
  const int srow   = lane >> 2;
  const int schunk = (lane & 3) ^ ((lane >> 3) & 3);
  const size_t aSrc0 = (size_t)(bm + wave * 16 + srow) * K + schunk * 8;
  const size_t aSrc1 = (size_t)(bm + 128 + wave * 16 + srow) * K + schunk * 8;
  const size_t bSrc0 = (size_t)(bn + wave * 16 + srow) * K + schunk * 8;
  const size_t bSrc1 = (size_t)(bn + 128 + wave * 16 + srow) * K + schunk * 8;

#define STAGE(KT)                                                              \
  do {                                                                         \
    const int _bo = ((KT) & 3) * 8192 + wave * 512;                            \
    const size_t _k = (size_t)(KT) << 5;                                       \
    __builtin_amdgcn_global_load_lds((const unsigned int*)(Ae + aSrc0 + _k),   \
                                     (unsigned int*)(ldsA + _bo), 16, 0, 0);   \
    __builtin_amdgcn_global_load_lds((const unsigned int*)(Ae + aSrc1 + _k),   \
                                     (unsigned int*)(ldsA + _bo + 4096), 16, 0, 0); \
    __builtin_amdgcn_global_load_lds((const unsigned int*)(Be + bSrc0 + _k),   \
                                     (unsigned int*)(ldsB + _bo), 16, 0, 0);   \
    __builtin_amdgcn_global_load_lds((const unsigned int*)(Be + bSrc1 + _k),   \
                                     (unsigned int*)(ldsB + _bo + 4096), 16, 0, 0); \
  } while (0)

  // ---- fragment read bases (elements), same swizzle as staging ----
  const int swz   = (fq ^ ((fr >> 1) & 3)) << 3;
  const int abase = (wm * 128 + fr) * 32 + swz;  // + mi*512
  const int bbase = (wn * 64 + fr) * 32 + swz;   // + ni*512

  f32x4 acc[8][4];
  const f32x4 zero = {0.f, 0.f, 0.f, 0.f};
#pragma unroll
  for (int i = 0; i < 8; ++i)
#pragma unroll
    for (int j = 0; j < 4; ++j) acc[i][j] = zero;

  const int nK = K >> 5;
  STAGE(0);
  if (nK > 1) STAGE(1);
  if (nK > 2) STAGE(2);

#pragma unroll 1
  for (int kt = 0; kt < nK; ++kt) {
    if (kt + 3 < nK) STAGE(kt + 3);
    // counted wait: tile kt resident once <=12 (3 tiles x 4 loads) outstanding
    asm volatile("s_waitcnt vmcnt(12)" ::: "memory");
    wg_barrier();  // all waves' staging of tile kt now visible

    const unsigned short* lA = ldsA + (kt & 3) * 8192;
    const unsigned short* lB = ldsB + (kt & 3) * 8192;

    // Issue ALL fragment reads up front (12 x ds_read_b128); compiler's
    // fine-grained lgkmcnt lets a1[] drain during the first MFMA cluster.
    bf16x8 a0[4], a1[4], b0[4];
#pragma unroll
    for (int i = 0; i < 4; ++i) a0[i] = *(const bf16x8*)&lA[abase + i * 512];
#pragma unroll
    for (int i = 0; i < 4; ++i) b0[i] = *(const bf16x8*)&lB[bbase + i * 512];
#pragma unroll
    for (int i = 0; i < 4; ++i)
      a1[i] = *(const bf16x8*)&lA[abase + 2048 + i * 512];

    __builtin_amdgcn_s_setprio(1);
#pragma unroll
    for (int mi = 0; mi < 4; ++mi)
#pragma unroll
      for (int ni = 0; ni < 4; ++ni)
        acc[mi][ni] = __builtin_amdgcn_mfma_f32_16x16x32_bf16(
            a0[mi], b0[ni], acc[mi][ni], 0, 0, 0);
#pragma unroll
    for (int mi = 0; mi < 4; ++mi)
#pragma unroll
      for (int ni = 0; ni < 4; ++ni)
        acc[4 + mi][ni] = __builtin_amdgcn_mfma_f32_16x16x32_bf16(
            a1[mi], b0[ni], acc[4 + mi][ni], 0, 0, 0);
    __builtin_amdgcn_s_setprio(0);
    wg_barrier();  // all waves done reading buf[kt&3] -> safe to recycle
  }
#undef STAGE

  // ---- epilogue. C/D layout: col = lane&15, row = (lane>>4)*4 + reg ----
  const int crow0 = bm + wm * 128 + fq * 4;
  const int ccol0 = bn + wn * 64 + fr;
  float bv[4];
#pragma unroll
  for (int ni = 0; ni < 4; ++ni) bv[ni] = bias[(size_t)e * N + ccol0 + ni * 16];

  if (RELU_BF16_OUT) {
    unsigned short* C = (unsigned short*)Cout + (size_t)e * M * N;
#pragma unroll
    for (int mi = 0; mi < 8; ++mi)
#pragma unroll
      for (int ni = 0; ni < 4; ++ni)
#pragma unroll
        for (int r = 0; r < 4; ++r) {
          float v = acc[mi][ni][r] + bv[ni];
          v = v > 0.f ? v : 0.f;
          C[(size_t)(crow0 + mi * 16 + r) * N + ccol0 + ni * 16] = f2bf(v);
        }
  } else {
    float* C = (float*)Cout + (size_t)e * M * N;
#pragma unroll
    for (int mi = 0; mi < 8; ++mi)
#pragma unroll
      for (int ni = 0; ni < 4; ++ni)
#pragma unroll
        for (int r = 0; r < 4; ++r) {
          C[(size_t)(crow0 + mi * 16 + r) * N + ccol0 + ni * 16] =
              acc[mi][ni][r] + bv[ni];
        }
  }
}

extern "C" void kernel_launch(void* const* d_in, const int* in_sizes, int n_in,
                              void* d_out, int out_size, void* d_ws, size_t ws_size,
                              hipStream_t stream) {
  (void)in_sizes; (void)n_in; (void)out_size; (void)ws_size;
  const float* xs = (const float*)d_in[0];
  // d_in[1] = fwd_expert_count: uniform N/E by construction, unused
  const float* w1 = (const float*)d_in[2];
  const float* b1 = (const float*)d_in[3];
  const float* w2 = (const float*)d_in[4];
  const float* b2 = (const float*)d_in[5];
  float* y = (float*)d_out;

  // ws layout: xs_bf 32MB | w_bf 128MB (w1 then w2) | h_bf 128MB  => 288MB
  char* ws = (char*)d_ws;
  unsigned short* xs_bf = (unsigned short*)ws;
  unsigned short* w_bf  = (unsigned short*)(ws + (size_t)(32u << 20));
  unsigned short* h_bf  = (unsigned short*)(ws + (size_t)(160u << 20));

  const int nXs = E_ * NPE * D_;  // 16,777,216
  const int nW  = E_ * H_ * D_;   // 67,108,864

  cvt_f32_to_bf16<<<2048, 256, 0, stream>>>(xs, xs_bf, nXs / 4);
  cvt_f32_to_bf16<<<2048, 256, 0, stream>>>(w1, w_bf, nW / 4);

  // GEMM1: h = relu(xs @ w1^T + b1), out bf16 [E][1024][4096]
  gemm_bt<true><<<E_ * (NPE / 256) * (H_ / 256), 512, 0, stream>>>(
      xs_bf, w_bf, b1, h_bf, NPE, H_, D_);

  cvt_f32_to_bf16<<<2048, 256, 0, stream>>>(w2, w_bf, nW / 4);

  // GEMM2: y = h @ w2^T + b2, out f32 [E][1024][1024]
  gemm_bt<false><<<E_ * (NPE / 256) * (D_ / 256), 512, 0, stream>>>(
      h_bf, w_bf, b2, y, NPE, D_, H_);
}

// Round 3
// 951.948 us; speedup vs baseline: 1.0539x; 1.0539x over previous
//
#include <hip/hip_runtime.h>

// Problem constants (reference: E,D,H,N = 16,1024,4096,16384; uniform counts)
#define E_  16
#define D_  1024
#define H_  4096
#define NPE 1024  // tokens per expert = N/E

typedef __bf16 bf16x8 __attribute__((ext_vector_type(8)));
typedef float f32x4 __attribute__((ext_vector_type(4)));

__device__ __forceinline__ unsigned short f2bf(float f) {
  unsigned int u = __float_as_uint(f);
  u += 0x7fffu + ((u >> 16) & 1u);  // RNE
  return (unsigned short)(u >> 16);
}

__device__ __forceinline__ ushort4 cvt4(float4 v) {
  ushort4 o;
  o.x = f2bf(v.x);
  o.y = f2bf(v.y);
  o.z = f2bf(v.z);
  o.w = f2bf(v.w);
  return o;
}

// fp32 -> bf16 convert. R3: manual 4-way independent unroll. R2's
// grid-stride-with-check kept 1 load in flight per thread -> latency-bound
// (~195us vs 64us roofline for the 402MB w-convert). 4 back-to-back loads
// per iteration = 4x memory-level parallelism -> BW-bound.
__global__ __launch_bounds__(256) void cvt_f32_to_bf16(
    const float* __restrict__ in, unsigned short* __restrict__ out, int nvec) {
  const int stride = gridDim.x * 256;
  int i = blockIdx.x * 256 + threadIdx.x;
  const int nmain = nvec - 3 * stride;
  for (; i < nmain; i += 4 * stride) {
    float4 v0 = ((const float4*)in)[i];
    float4 v1 = ((const float4*)in)[i + stride];
    float4 v2 = ((const float4*)in)[i + 2 * stride];
    float4 v3 = ((const float4*)in)[i + 3 * stride];
    ((ushort4*)out)[i]              = cvt4(v0);
    ((ushort4*)out)[i + stride]     = cvt4(v1);
    ((ushort4*)out)[i + 2 * stride] = cvt4(v2);
    ((ushort4*)out)[i + 3 * stride] = cvt4(v3);
  }
  for (; i < nvec; i += stride)  // tail (sizes here divide exactly; unused)
    ((ushort4*)out)[i] = cvt4(((const float4*)in)[i]);
}

// Raw workgroup barrier with compiler memory fences on both sides.
__device__ __forceinline__ void wg_barrier() {
  asm volatile("" ::: "memory");
  __builtin_amdgcn_s_barrier();
  asm volatile("" ::: "memory");
}

// Batched NT GEMM: C[e] = A[e] (MxK row-major) * B[e]^T (B NxK row-major)
//                  + bias[e], optional ReLU + bf16 output.
//
// R3 structure: BM x 256 tile (BM=256 or 128), BK=32, 512 threads = 8 waves
// (2M x 4N), wave tile (BM/2)x64 = acc[BM/32][4]. TWO LDS buffers only
// (BM=256: 64KB, BM=128: 48KB) -> 2 blocks/CU CO-RESIDENT. R2's cycle
// accounting (3843 cyc/K-tile vs MFMA 1242 + LDS 1413 + VALU 645 even
// fully serial) showed 1 block/CU lockstep leaves every pipe idle while
// all 8 waves sit at the same barrier. With 2 blocks at opposite barrier
// phases, block Y's MFMA/ds_read fills the pipes while block X barriers
// (m114/m97 mechanism: implicit wave-level overlap at >=2 blocks/CU).
//
// Loop per K-tile: vmcnt(0) [own stage loads of kt, issued one full tile
// ago -> latency covered] -> barrier#1 [all waves' kt staging visible] ->
// STAGE(kt+1) into buf^1 -> all 12/8 ds_reads -> setprio(1) MFMA cluster
// setprio(0) -> barrier#2 [all waves done reading buf -> recyclable].
// Compiler schedules fine-grained lgkmcnt between reads and MFMAs (m97).
//
// Buffer recycle: STAGE(kt+1) writes buf^1, whose last reads (tile kt-1)
// completed before their consuming MFMAs, which precede barrier#2(kt-1)
// <= barrier#1(kt) < STAGE(kt+1). Race-free via barrier#2.
//
// Staging: flat 16B-chunk id c = t*512 + tid over [A rows | B rows];
// A/B boundary at c=BM*4 is t-aligned for BM in {128,256} (wave-uniform
// branch, wave-uniform LDS dest base). Source chunk pre-swizzled
// q = (c&3) ^ ((row>>1)&3)  (T2; R1/R2: SQ_LDS_BANK_CONFLICT == 0).
template <int BM, bool RELU_BF16_OUT>
__global__ __launch_bounds__(512, 2) void gemm_bt(
    const unsigned short* __restrict__ A,   // [E][M][K] bf16
    const unsigned short* __restrict__ B,   // [E][N][K] bf16
    const float* __restrict__ bias,         // [E][N]
    void* __restrict__ Cout,                // [E][M][N] bf16 or f32
    int M, int N, int K) {
  constexpr int BN    = 256;
  constexpr int MR    = BM / 32;            // acc row-frags per wave
  constexpr int LOADS = (BM + BN) / 128;    // stage loads per thread per tile
  constexpr int BUFE  = (BM + BN) * 32;     // elements per LDS buffer
  __shared__ __attribute__((aligned(16))) unsigned short lds[2][BUFE];

  const int tid  = threadIdx.x;
  const int lane = tid & 63;
  const int wave = tid >> 6;   // 0..7
  const int wm   = wave >> 2;  // 0..1
  const int wn   = wave & 3;   // 0..3
  const int fr   = lane & 15;
  const int fq   = lane >> 4;

  // ---- XCD-aware tile decode (1D grid: E * Mt * Nt blocks) ----
  const int Mt = M / BM;
  const int Nt = N >> 8;
  const int id     = blockIdx.x;
  const int region = id & 7;       // dispatch round-robins XCDs (R1-measured)
  const int slot   = id >> 3;
  const int bpe    = Mt * Nt;
  const int eloc   = slot / bpe;
  const int rem    = slot - eloc * bpe;
  const int e      = region * (E_ / 8) + eloc;
  const int SN     = Nt < 2 ? Nt : 2;
  const int csz    = Mt * SN;
  const int chunk  = rem / csz;
  const int inner  = rem - chunk * csz;
  const int mt     = inner % Mt;
  const int nt     = chunk * SN + inner / Mt;

  const int bm = mt * BM;
  const int bn = nt << 8;

  const unsigned short* Ae = A + (size_t)e * M * K;
  const unsigned short* Be = B + (size_t)e * N * K;

  // ---- staging addresses (per-thread global src, wave-uniform LDS dest) ----
  const unsigned short* gsrc[LOADS];
  unsigned short* l0[LOADS];
#pragma unroll
  for (int t = 0; t < LOADS; ++t) {
    const int c   = t * 512 + tid;
    const bool isA = c < BM * 4;
    const int cl  = isA ? c : c - BM * 4;
    const int r   = cl >> 2;
    const int q   = (cl & 3) ^ ((r >> 1) & 3);
    gsrc[t] = (isA ? Ae + (size_t)(bm + r) * K : Be + (size_t)(bn + r) * K) + q * 8;
    l0[t]   = &lds[0][0] + t * 4096 + wave * 512;  // A at c*8, B at BM*128+cl*8 == c*8
  }

#define STAGE(KT, BUF)                                                         \
  do {                                                                         \
    const int _bs = (BUF) * BUFE;                                              \
    const size_t _k = (size_t)(KT) << 5;                                       \
    _Pragma("unroll")                                                          \
    for (int t = 0; t < LOADS; ++t)                                            \
      __builtin_amdgcn_global_load_lds((const unsigned int*)(gsrc[t] + _k),    \
                                       (unsigned int*)(l0[t] + _bs), 16, 0, 0);\
  } while (0)

  // ---- fragment read offsets (elements), same swizzle as staging ----
  const int swz  = (fq ^ ((fr >> 1) & 3)) << 3;
  const int aoff = (wm * (BM / 2) + fr) * 32 + swz;          // + mi*512
  const int boff = BM * 32 + (wn * 64 + fr) * 32 + swz;      // + ni*512

  f32x4 acc[MR][4];
  const f32x4 zero = {0.f, 0.f, 0.f, 0.f};
#pragma unroll
  for (int i = 0; i < MR; ++i)
#pragma unroll
    for (int j = 0; j < 4; ++j) acc[i][j] = zero;

  const int nK = K >> 5;
  STAGE(0, 0);
  int buf = 0;

#pragma unroll 1
  for (int kt = 0; kt < nK; ++kt) {
    // own stage loads of tile kt were issued a full K-tile ago
    asm volatile("s_waitcnt vmcnt(0)" ::: "memory");
    wg_barrier();  // all waves' staging of tile kt visible
    if (kt + 1 < nK) STAGE(kt + 1, buf ^ 1);

    const unsigned short* L = &lds[0][0] + buf * BUFE;
    bf16x8 af[MR], bfv[4];
#pragma unroll
    for (int i = 0; i < MR; ++i) af[i] = *(const bf16x8*)&L[aoff + i * 512];
#pragma unroll
    for (int i = 0; i < 4; ++i) bfv[i] = *(const bf16x8*)&L[boff + i * 512];

    __builtin_amdgcn_s_setprio(1);
#pragma unroll
    for (int mi = 0; mi < MR; ++mi)
#pragma unroll
      for (int ni = 0; ni < 4; ++ni)
        acc[mi][ni] = __builtin_amdgcn_mfma_f32_16x16x32_bf16(
            af[mi], bfv[ni], acc[mi][ni], 0, 0, 0);
    __builtin_amdgcn_s_setprio(0);
    wg_barrier();  // all waves done reading buf -> safe to recycle
    buf ^= 1;
  }
#undef STAGE

  // ---- epilogue. C/D layout: col = lane&15, row = (lane>>4)*4 + reg ----
  const int crow0 = bm + wm * (BM / 2) + fq * 4;
  const int ccol0 = bn + wn * 64 + fr;
  float bv[4];
#pragma unroll
  for (int ni = 0; ni < 4; ++ni) bv[ni] = bias[(size_t)e * N + ccol0 + ni * 16];

  if (RELU_BF16_OUT) {
    unsigned short* C = (unsigned short*)Cout + (size_t)e * M * N;
#pragma unroll
    for (int mi = 0; mi < MR; ++mi)
#pragma unroll
      for (int ni = 0; ni < 4; ++ni)
#pragma unroll
        for (int r = 0; r < 4; ++r) {
          float v = acc[mi][ni][r] + bv[ni];
          v = v > 0.f ? v : 0.f;
          C[(size_t)(crow0 + mi * 16 + r) * N + ccol0 + ni * 16] = f2bf(v);
        }
  } else {
    float* C = (float*)Cout + (size_t)e * M * N;
#pragma unroll
    for (int mi = 0; mi < MR; ++mi)
#pragma unroll
      for (int ni = 0; ni < 4; ++ni)
#pragma unroll
        for (int r = 0; r < 4; ++r) {
          C[(size_t)(crow0 + mi * 16 + r) * N + ccol0 + ni * 16] =
              acc[mi][ni][r] + bv[ni];
        }
  }
}

extern "C" void kernel_launch(void* const* d_in, const int* in_sizes, int n_in,
                              void* d_out, int out_size, void* d_ws, size_t ws_size,
                              hipStream_t stream) {
  (void)in_sizes; (void)n_in; (void)out_size; (void)ws_size;
  const float* xs = (const float*)d_in[0];
  // d_in[1] = fwd_expert_count: uniform N/E by construction, unused
  const float* w1 = (const float*)d_in[2];
  const float* b1 = (const float*)d_in[3];
  const float* w2 = (const float*)d_in[4];
  const float* b2 = (const float*)d_in[5];
  float* y = (float*)d_out;

  // ws layout: xs_bf 32MB | w_bf 128MB | h_bf 128MB  => 288MB
  char* ws = (char*)d_ws;
  unsigned short* xs_bf = (unsigned short*)ws;
  unsigned short* w_bf  = (unsigned short*)(ws + (size_t)(32u << 20));
  unsigned short* h_bf  = (unsigned short*)(ws + (size_t)(160u << 20));

  const int nXs = E_ * NPE * D_;  // 16,777,216
  const int nW  = E_ * H_ * D_;   // 67,108,864

  cvt_f32_to_bf16<<<2048, 256, 0, stream>>>(xs, xs_bf, nXs / 4);
  cvt_f32_to_bf16<<<2048, 256, 0, stream>>>(w1, w_bf, nW / 4);

  // GEMM1: h = relu(xs @ w1^T + b1), out bf16 [E][1024][4096]
  // 256x256 tile -> grid 16*4*16 = 1024 blocks, 2 blocks/CU (64KB LDS each)
  gemm_bt<256, true><<<E_ * (NPE / 256) * (H_ / 256), 512, 0, stream>>>(
      xs_bf, w_bf, b1, h_bf, NPE, H_, D_);

  cvt_f32_to_bf16<<<2048, 256, 0, stream>>>(w2, w_bf, nW / 4);

  // GEMM2: y = h @ w2^T + b2, out f32 [E][1024][1024]
  // 128x256 tile -> grid 16*8*4 = 512 blocks, 2 blocks/CU (48KB LDS each)
  gemm_bt<128, false><<<E_ * (NPE / 128) * (D_ / 256), 512, 0, stream>>>(
      h_bf, w_bf, b2, y, NPE, D_, H_);
}